// Round 16
// baseline (216.846 us; speedup 1.0000x reference)
//
#include <hip/hip_runtime.h>
#include <hip/hip_bf16.h>
#include <math.h>

// ---------------- problem constants ----------------
#define D_MODEL 1024
#define D_STATE 16
#define D_CONV  4
#define D_INNER 2048
#define DT_RANK 64
#define LSEQ    1024

typedef short bf16x8 __attribute__((ext_vector_type(8)));
typedef float f32x4  __attribute__((ext_vector_type(4)));

typedef const __attribute__((address_space(1))) unsigned int* gp1_t;
typedef __attribute__((address_space(3))) unsigned int* lp3_t;

__device__ __forceinline__ float softplus_f(float x) {
    const float sp = __logf(1.f + __expf(x));
    return (x > 20.f) ? x : sp;
}
__device__ __forceinline__ float silu_f(float x) {
    return x / (1.f + __expf(-x));
}
__device__ __forceinline__ unsigned short f2bf(float f) {
    union { float f; unsigned int u; } c; c.f = f;
    const unsigned int u = c.u;
    return (unsigned short)((u + 0x7FFFu + ((u >> 16) & 1u)) >> 16);
}

// ---------------- fused fp32->bf16 convert of all 4 GEMM inputs ----------------
__global__ __launch_bounds__(256)
void cvt_all_k(const float* __restrict__ w0, const float* __restrict__ xx,
               const float* __restrict__ w1, const float* __restrict__ xx1,
               unsigned short* __restrict__ WB, unsigned short* __restrict__ XB,
               unsigned short* __restrict__ WB1, unsigned short* __restrict__ X1B)
{
    const int i = blockIdx.x * 256 + threadIdx.x;
    const float* src; unsigned short* dst; int j;
    if (i < (1 << 20))            { src = w0;  dst = WB;  j = i; }
    else if (i < (5 << 18))       { src = xx;  dst = XB;  j = i - (1 << 20); }
    else if (i < (7 << 18))       { src = w1;  dst = WB1; j = i - (5 << 18); }
    else                          { src = xx1; dst = X1B; j = i - (7 << 18); }
    const float4 v = *(const float4*)&src[(size_t)j * 4];
    ushort4 o;
    o.x = f2bf(v.x); o.y = f2bf(v.y); o.z = f2bf(v.z); o.w = f2bf(v.w);
    *(ushort4*)&dst[(size_t)j * 4] = o;
}

// ---------------- transpose+add+convert REST[l][d] AND OWB convert (merged) ----------------
__global__ __launch_bounds__(256)
void cvtT_add_owb_k(const float* __restrict__ r0, const float* __restrict__ r1,
                    unsigned short* __restrict__ dst,
                    const float* __restrict__ ow, unsigned short* __restrict__ OWB)
{
    const int bx = blockIdx.x;
    if (bx >= 2048) {
        const int i = (bx - 2048) * 256 + threadIdx.x;
        const float4 v = *(const float4*)&ow[(size_t)i * 4];
        ushort4 o;
        o.x = f2bf(v.x); o.y = f2bf(v.y); o.z = f2bf(v.z); o.w = f2bf(v.w);
        *(ushort4*)&OWB[(size_t)i * 4] = o;
        return;
    }
    __shared__ float s[32][33];
    const int tx = threadIdx.x & 31, ty = threadIdx.x >> 5;
    const int lBase = (bx & 31) * 32, dBase = (bx >> 5) * 32;
    #pragma unroll
    for (int i = 0; i < 4; ++i) {
        const int d = dBase + ty + i * 8;
        const size_t off = (size_t)d * LSEQ + lBase + tx;
        s[ty + i * 8][tx] = r0[off] + r1[off];
    }
    __syncthreads();
    #pragma unroll
    for (int i = 0; i < 4; ++i) {
        const int l = lBase + ty + i * 8;
        dst[(size_t)l * D_INNER + dBase + tx] = f2bf(s[tx][ty + i * 8]);
    }
}

// ---------------- bf16 MFMA GEMM core (NT), 128x64 tile, 4 waves (2x2 of 64x32) ----------------
__device__ __forceinline__
void mfma_tile64(const unsigned short* __restrict__ A, const unsigned short* __restrict__ B,
                 float* __restrict__ C, int N, int K, int lda, int mBase, int nBase, int siluRow)
{
    __shared__ unsigned short AsL[128 * 32];
    __shared__ unsigned short BsL[64 * 32];
    const int tid = threadIdx.x;
    const int lane = tid & 63, w = tid >> 6;
    const int wr = w >> 1, wc = w & 1;
    const int l15 = lane & 15, l4 = lane >> 4;

    f32x4 acc[4][2] = {};
    const int stRow = tid >> 2;
    const int stCol = (tid & 3) * 8;
    const int ldsOff = w * 512;

    for (int kb = 0; kb < K; kb += 32) {
        #pragma unroll
        for (int it = 0; it < 2; ++it) {
            const int r = it * 64 + stRow;
            __builtin_amdgcn_global_load_lds(
                (gp1_t)&A[(size_t)(mBase + r) * lda + kb + stCol],
                (lp3_t)&AsL[it * 2048 + ldsOff], 16, 0, 0);
        }
        __builtin_amdgcn_global_load_lds(
            (gp1_t)&B[(size_t)(nBase + stRow) * lda + kb + stCol],
            (lp3_t)&BsL[ldsOff], 16, 0, 0);
        __syncthreads();
        bf16x8 af[4], bfr[2];
        #pragma unroll
        for (int i = 0; i < 4; ++i)
            af[i] = *(const bf16x8*)&AsL[(wr * 64 + i * 16 + l15) * 32 + l4 * 8];
        #pragma unroll
        for (int j = 0; j < 2; ++j)
            bfr[j] = *(const bf16x8*)&BsL[(wc * 32 + j * 16 + l15) * 32 + l4 * 8];
        #pragma unroll
        for (int i = 0; i < 4; ++i)
            #pragma unroll
            for (int j = 0; j < 2; ++j)
                acc[i][j] = __builtin_amdgcn_mfma_f32_16x16x32_bf16(af[i], bfr[j], acc[i][j], 0, 0, 0);
        __syncthreads();
    }

    #pragma unroll
    for (int i = 0; i < 4; ++i) {
        const int row0 = mBase + wr * 64 + i * 16 + l4 * 4;
        #pragma unroll
        for (int j = 0; j < 2; ++j) {
            const int col = nBase + wc * 32 + j * 16 + l15;
            #pragma unroll
            for (int r = 0; r < 4; ++r) {
                float v = acc[i][j][r];
                if (row0 + r >= siluRow) v = silu_f(v);
                C[(size_t)(row0 + r) * N + col] = v;
            }
        }
    }
}

__global__ __launch_bounds__(256)
void mfma_in_k(const unsigned short* __restrict__ WB, const unsigned short* __restrict__ XB,
               const unsigned short* __restrict__ WB1, const unsigned short* __restrict__ X1B,
               float* __restrict__ XZ, float* __restrict__ X1P)
{
    const int by = blockIdx.y;
    if (by < 32)
        mfma_tile64(WB, XB, XZ, 1024, 1024, 1024, by * 128, blockIdx.x * 64, 2048);
    else
        mfma_tile64(WB1, X1B, X1P, 1024, 1024, 1024, (by - 32) * 128, blockIdx.x * 64, 1 << 30);
}

__global__ __launch_bounds__(256)
void mfma_out_k(const unsigned short* __restrict__ RESTB, const unsigned short* __restrict__ OWB,
                float* __restrict__ P4)
{
    const int z = blockIdx.z;
    mfma_tile64(RESTB + z * 512, OWB + z * 512, P4 + (size_t)z * (1 << 20),
                1024, 512, 2048, blockIdx.y * 128, blockIdx.x * 64, 1 << 30);
}

__global__ __launch_bounds__(256)
void reduce4_k(const float* __restrict__ P, float* __restrict__ out)
{
    const int i = blockIdx.x * 256 + threadIdx.x;
    const size_t o = (size_t)i * 4;
    float4 s = *(const float4*)&P[o];
    #pragma unroll
    for (int z = 1; z < 4; ++z) {
        const float4 v = *(const float4*)&P[(size_t)z * (1 << 20) + o];
        s.x += v.x; s.y += v.y; s.z += v.z; s.w += v.w;
    }
    *(float4*)&out[o] = s;
}

// ---------------- x_proj split-K, single launch ----------------
constexpr int TS = 64;
constexpr int KT = 16;
constexpr int LP = 4;

__global__ __launch_bounds__(256)
void xproj_k(const float* __restrict__ xw0, const float* __restrict__ co0,
             const float* __restrict__ xw1, const float* __restrict__ co1,
             float* __restrict__ P0, float* __restrict__ P1)
{
    const int br = blockIdx.z >> 3;
    const int sl = blockIdx.z & 7;
    const float* A = (br ? xw1 : xw0) + sl * 256;
    const float* B = (br ? co1 : co0) + (size_t)sl * 256 * LSEQ;
    float* C = (br ? P1 : P0) + (size_t)sl * 96 * LSEQ;

    __shared__ float As[KT][TS + LP];
    __shared__ float BsL[16 * 64];
    const int tid = threadIdx.x;
    const int tx = tid & 15, ty = tid >> 4;
    const int mBase = blockIdx.y * TS;
    const int nBase = blockIdx.x * TS;

    float acc[4][4] = {};
    const int ar = tid >> 2;
    const int ak = (tid & 3) * 4;
    const int ldsOffB = (tid >> 6) * 256;

    for (int kb = 0; kb < 256; kb += KT) {
        {
            const int gm = mBase + ar;
            float4 av = make_float4(0.f, 0.f, 0.f, 0.f);
            if (gm < 96) av = *(const float4*)&A[(size_t)gm * D_INNER + kb + ak];
            As[ak + 0][ar] = av.x;
            As[ak + 1][ar] = av.y;
            As[ak + 2][ar] = av.z;
            As[ak + 3][ar] = av.w;
        }
        __builtin_amdgcn_global_load_lds(
            (gp1_t)&B[(size_t)(kb + (tid >> 4)) * LSEQ + nBase + (tid & 15) * 4],
            (lp3_t)&BsL[ldsOffB], 16, 0, 0);
        __syncthreads();
        #pragma unroll
        for (int k = 0; k < KT; ++k) {
            float4 a = *(const float4*)&As[k][ty * 4];
            float4 b = *(const float4*)&BsL[k * 64 + tx * 4];
            float av[4] = {a.x, a.y, a.z, a.w};
            float bv[4] = {b.x, b.y, b.z, b.w};
            #pragma unroll
            for (int i = 0; i < 4; ++i)
                #pragma unroll
                for (int j = 0; j < 4; ++j)
                    acc[i][j] = fmaf(av[i], bv[j], acc[i][j]);
        }
        __syncthreads();
    }

    #pragma unroll
    for (int i = 0; i < 4; ++i) {
        const int m = mBase + ty * 4 + i;
        if (m >= 96) continue;
        #pragma unroll
        for (int j = 0; j < 4; ++j)
            C[(size_t)m * LSEQ + nBase + tx * 4 + j] = acc[i][j];
    }
}

// ---------------- reduce split-K partials + transpose + interleave B/C ----------------
__global__ __launch_bounds__(256)
void reduceT_k(const float* __restrict__ P0, const float* __restrict__ P1,
               float* __restrict__ xdT0, float* __restrict__ xdT1)
{
    const int idx = blockIdx.x * 256 + threadIdx.x;
    const int k = idx & 127;
    const int l = (idx >> 7) & (LSEQ - 1);
    const int br = idx >> 17;
    if (k >= 96) return;
    const int srck = (k < 64) ? k : (64 + ((k - 64) >> 1) + ((k & 1) << 4));
    const float* P = br ? P1 : P0;
    float s = 0.f;
    #pragma unroll
    for (int sl = 0; sl < 8; ++sl)
        s += P[(size_t)sl * 96 * LSEQ + (size_t)srck * LSEQ + l];
    float* o = br ? xdT1 : xdT0;
    o[(size_t)l * 96 + k] = s;
}

// ---------------- dt_proj (both branches) + fused softplus ----------------
__global__ __launch_bounds__(256)
void dtproj_k(const float* __restrict__ dtw0, const float* __restrict__ xdT0,
              const float* __restrict__ dtw1, const float* __restrict__ xdT1,
              float* __restrict__ SP0, float* __restrict__ SP1)
{
    const int br = blockIdx.z;
    const float* A = br ? dtw1 : dtw0;
    const float* B = br ? xdT1 : xdT0;
    float* C = br ? SP1 : SP0;

    __shared__ float As[KT][TS + LP];
    __shared__ float Bs[KT][TS + LP];
    const int tid = threadIdx.x;
    const int tx = tid & 15, ty = tid >> 4;
    const int mBase = blockIdx.y * TS;
    const int nBase = blockIdx.x * TS;

    float acc[4][4] = {};
    const int ar = tid >> 2;
    const int ak = (tid & 3) * 4;

    for (int kb = 0; kb < DT_RANK; kb += KT) {
        {
            const float4 av = *(const float4*)&A[(size_t)(mBase + ar) * DT_RANK + kb + ak];
            As[ak + 0][ar] = av.x;
            As[ak + 1][ar] = av.y;
            As[ak + 2][ar] = av.z;
            As[ak + 3][ar] = av.w;
        }
        {
            const float4 bv = *(const float4*)&B[(size_t)(nBase + ar) * 96 + kb + ak];
            Bs[ak + 0][ar] = bv.x;
            Bs[ak + 1][ar] = bv.y;
            Bs[ak + 2][ar] = bv.z;
            Bs[ak + 3][ar] = bv.w;
        }
        __syncthreads();
        #pragma unroll
        for (int k = 0; k < KT; ++k) {
            float4 a = *(const float4*)&As[k][ty * 4];
            float4 b = *(const float4*)&Bs[k][tx * 4];
            float av[4] = {a.x, a.y, a.z, a.w};
            float bv[4] = {b.x, b.y, b.z, b.w};
            #pragma unroll
            for (int i = 0; i < 4; ++i)
                #pragma unroll
                for (int j = 0; j < 4; ++j)
                    acc[i][j] = fmaf(av[i], bv[j], acc[i][j]);
        }
        __syncthreads();
    }

    #pragma unroll
    for (int i = 0; i < 4; ++i)
        #pragma unroll
        for (int j = 0; j < 4; ++j)
            C[(size_t)(mBase + ty * 4 + i) * LSEQ + nBase + tx * 4 + j] = softplus_f(acc[i][j]);
}

// ---------------- depthwise causal conv1d + SiLU ----------------
__global__ __launch_bounds__(256)
void conv_silu_k(const float* __restrict__ xa, const float* __restrict__ x1p,
                 const float* __restrict__ w0, const float* __restrict__ b0,
                 const float* __restrict__ w1, const float* __restrict__ b1,
                 float* __restrict__ co0, float* __restrict__ co1)
{
    const int idx = blockIdx.x * blockDim.x + threadIdx.x;
    const int br  = idx >> 21;
    const int rem = idx & ((1 << 21) - 1);
    const int d = rem >> 10;
    const int l = rem & (LSEQ - 1);

    const float* xin = br ? x1p : xa;
    const float* w   = br ? w1 : w0;
    const float* bb  = br ? b1 : b0;
    float* out       = br ? co1 : co0;

    const float* row = xin + (size_t)d * LSEQ;
    float acc = bb[d];
    #pragma unroll
    for (int j = 0; j < D_CONV; ++j) {
        const int li = l - (D_CONV - 1) + j;
        const float xv = (li >= 0) ? row[li] : 0.f;
        acc = fmaf(w[d * D_CONV + j], xv, acc);
    }
    out[rem] = silu_f(acc);
}

// ---------------- chunk-parallel scan: 2 ch/block, 256 thr (16c x 16n), chunk 64 ----------------
// 2048 blocks x 4 waves -> 8 blocks/CU co-resident (32-wave cap) -> finer drain, higher Occ.
// Identical arithmetic to scan10; coalesced LDS-buffered stores.
__global__ __launch_bounds__(256)
void scan11_k(const float* __restrict__ sp0, const float* __restrict__ u0,
              const float* __restrict__ xdT0,
              const float* __restrict__ Al0, const float* __restrict__ Dk0,
              const float* __restrict__ sp1, const float* __restrict__ u1,
              const float* __restrict__ xdT1,
              const float* __restrict__ Al1, const float* __restrict__ Dk1,
              const float* __restrict__ gz,
              float* __restrict__ res0, float* __restrict__ res1)
{
    const int d0  = blockIdx.x * 2;
    const int br  = blockIdx.y;
    const int tid = threadIdx.x;
    const int n   = tid & 15;
    const int c   = tid >> 4;          // 0..15

    const float* __restrict__ sp  = br ? sp1  : sp0;
    const float* __restrict__ u   = br ? u1   : u0;
    const float* __restrict__ xdT = br ? xdT1 : xdT0;
    const float* __restrict__ Al  = br ? Al1  : Al0;
    const float* __restrict__ Dk  = br ? Dk1  : Dk0;
    float* __restrict__ res       = br ? res1 : res0;

    float Adn[2], Dd[2];
    const float* srow[2]; const float* urow[2]; const float* grow[2]; float* orow[2];
    #pragma unroll
    for (int g = 0; g < 2; ++g) {
        Adn[g] = -__expf(Al[(d0 + g) * D_STATE + n]);
        Dd[g]  = Dk[d0 + g];
        srow[g] = sp + (size_t)(d0 + g) * LSEQ;
        urow[g] = u  + (size_t)(d0 + g) * LSEQ;
        grow[g] = gz + (size_t)(d0 + g) * LSEQ;
        orow[g] = res + (size_t)(d0 + g) * LSEQ;
    }
    const float* __restrict__ bc = xdT + 64 + 2 * n;
    const int t0 = c * 64;

    // ---- phase 1: chunk-local (a, b) per channel
    float a[2] = {1.f, 1.f};
    float b[2] = {0.f, 0.f};
    for (int tt = 0; tt < 64; tt += 4) {
        float2 bcv[4];
        #pragma unroll
        for (int j = 0; j < 4; ++j)
            bcv[j] = *(const float2*)&bc[(size_t)(t0 + tt + j) * 96];
        #pragma unroll
        for (int g = 0; g < 2; ++g) {
            const float4 s4 = *(const float4*)&srow[g][t0 + tt];
            const float4 u4 = *(const float4*)&urow[g][t0 + tt];
            const float sps[4] = {s4.x, s4.y, s4.z, s4.w};
            const float uvs[4] = {u4.x, u4.y, u4.z, u4.w};
            #pragma unroll
            for (int j = 0; j < 4; ++j) {
                const float dA = __expf(sps[j] * Adn[g]);
                a[g] *= dA;
                b[g] = fmaf(dA, b[g], sps[j] * uvs[j] * bcv[j].x);
            }
        }
    }

    __shared__ float sAm[16][16][2];
    __shared__ float sBm[16][16][2];
    __shared__ float sHm[16][16][2];
    __shared__ float yBuf[2][1024];
    #pragma unroll
    for (int g = 0; g < 2; ++g) { sAm[c][n][g] = a[g]; sBm[c][n][g] = b[g]; }
    __syncthreads();

    // ---- phase 2: serial exclusive scan over 16 chunks (32 threads: one per (n, g))
    if (tid < 32) {
        const int n2 = tid & 15, g2 = tid >> 4;
        float hb = 0.f;
        #pragma unroll
        for (int cc = 0; cc < 16; ++cc) {
            sHm[cc][n2][g2] = hb;
            hb = fmaf(sAm[cc][n2][g2], hb, sBm[cc][n2][g2]);
        }
    }
    __syncthreads();

    // ---- phase 3: re-run chunk from h_start; y -> LDS buffer
    float h[2];
    #pragma unroll
    for (int g = 0; g < 2; ++g) h[g] = sHm[c][n][g];

    for (int tt = 0; tt < 64; tt += 4) {
        float2 bcv[4];
        #pragma unroll
        for (int j = 0; j < 4; ++j)
            bcv[j] = *(const float2*)&bc[(size_t)(t0 + tt + j) * 96];
        #pragma unroll
        for (int g = 0; g < 2; ++g) {
            const float4 s4 = *(const float4*)&srow[g][t0 + tt];
            const float4 u4 = *(const float4*)&urow[g][t0 + tt];
            const float4 g4 = *(const float4*)&grow[g][t0 + tt];
            const float sps[4] = {s4.x, s4.y, s4.z, s4.w};
            const float uvs[4] = {u4.x, u4.y, u4.z, u4.w};
            const float gzs[4] = {g4.x, g4.y, g4.z, g4.w};
            float y4[4];
            #pragma unroll
            for (int j = 0; j < 4; ++j) {
                const float dA = __expf(sps[j] * Adn[g]);
                h[g] = fmaf(dA, h[g], sps[j] * uvs[j] * bcv[j].x);
                float y = h[g] * bcv[j].y;
                y += __shfl_xor(y, 1);
                y += __shfl_xor(y, 2);
                y += __shfl_xor(y, 4);
                y += __shfl_xor(y, 8);
                y4[j] = y;
            }
            if (n == 0) {
                float4 o;
                float* op = (float*)&o;
                #pragma unroll
                for (int j = 0; j < 4; ++j)
                    op[j] = (y4[j] + Dd[g] * uvs[j]) * gzs[j];
                *(float4*)&yBuf[g][t0 + tt] = o;
            }
        }
    }
    __syncthreads();

    // ---- coalesced store: 256 threads x 2 float4 = 2 channels x 4 KB contiguous
    #pragma unroll
    for (int r = 0; r < 2; ++r) {
        const int i = tid + r * 256;       // 0..511 float4 index
        const int g2 = i >> 8;             // 0..1
        const int i4 = (i & 255) << 2;     // 0..1020
        *(float4*)&orow[g2][i4] = *(const float4*)&yBuf[g2][i4];
    }
}

// ---------------- launcher ----------------
extern "C" void kernel_launch(void* const* d_in, const int* in_sizes, int n_in,
                              void* d_out, int out_size, void* d_ws, size_t ws_size,
                              hipStream_t stream)
{
    const float* x          = (const float*)d_in[0];
    const float* x1         = (const float*)d_in[1];
    const float* in_proj_w  = (const float*)d_in[2];
    const float* in_proj1_w = (const float*)d_in[3];
    const float* conv_w     = (const float*)d_in[4];
    const float* conv_b     = (const float*)d_in[5];
    const float* conv1_w    = (const float*)d_in[6];
    const float* conv1_b    = (const float*)d_in[7];
    const float* x_proj_w   = (const float*)d_in[8];
    const float* x_proj1_w  = (const float*)d_in[9];
    const float* dt_proj_w  = (const float*)d_in[10];
    const float* dt_proj1_w = (const float*)d_in[11];
    const float* A_log      = (const float*)d_in[12];
    const float* A_log1     = (const float*)d_in[13];
    const float* Dskip      = (const float*)d_in[14];
    const float* Dskip1     = (const float*)d_in[15];
    const float* out_proj_w = (const float*)d_in[16];

    float* ws = (float*)d_ws;
    const size_t CH = (size_t)D_INNER * LSEQ;
    const size_t XD = (size_t)96 * LSEQ;
    const size_t F  = 5 * CH + 2 * XD;

    float* XA    = ws;
    float* RES0  = ws;                   // over dead xa
    float* GZ    = ws + CH;
    float* X1P   = ws + 2 * CH;
    float* RES1  = ws + 2 * CH;          // over dead x1p
    float* CO0   = ws + 3 * CH;
    float* CO1   = ws + 4 * CH;
    float* P4    = ws + 3 * CH;          // out_proj split-K partials over dead co0/co1
    float* XDT0  = ws + 5 * CH;
    float* XDT1  = XDT0 + XD;
    float* XZ    = ws;

    unsigned short* WB  = (unsigned short*)(ws + F);
    unsigned short* XB  = (unsigned short*)(ws + F + 2097152);
    unsigned short* WB1 = (unsigned short*)(ws + F + 2097152 + 524288);
    unsigned short* X1B = (unsigned short*)(ws + F + 2097152 + 524288 + 1048576);
    float* P0  = ws + F;
    float* P1  = P0 + 8 * XD;
    float* SP0 = ws + F;
    float* SP1 = ws + F + CH;
    unsigned short* OWB   = (unsigned short*)(ws + F);
    unsigned short* RESTB = (unsigned short*)(ws + F + CH / 2);

    float* out = (float*)d_out;

    // 1) convert all four GEMM inputs to bf16
    hipLaunchKernelGGL(cvt_all_k, dim3((2 << 20) / 256), dim3(256), 0, stream,
                       in_proj_w, x, in_proj1_w, x1, WB, XB, WB1, X1B);

    // 2) in_proj + in_proj1 (merged bf16 MFMA, 128x64 tiles, 768 blocks = 3/CU)
    hipLaunchKernelGGL(mfma_in_k, dim3(16, 48), dim3(256), 0, stream,
                       WB, XB, WB1, X1B, XZ, X1P);

    // 3) causal conv + silu
    hipLaunchKernelGGL(conv_silu_k, dim3(2 * D_INNER * LSEQ / 256), dim3(256), 0, stream,
                       XA, X1P, conv_w, conv_b, conv1_w, conv1_b, CO0, CO1);

    // 4) x_proj split-K (one launch, 512 blocks)
    hipLaunchKernelGGL(xproj_k, dim3(LSEQ / TS, 2, 16), dim3(256), 0, stream,
                       x_proj_w, CO0, x_proj1_w, CO1, P0, P1);

    // 5) reduce partials -> xdT [L][96] interleaved
    hipLaunchKernelGGL(reduceT_k, dim3(2 * LSEQ * 128 / 256), dim3(256), 0, stream,
                       P0, P1, XDT0, XDT1);

    // 6) dt_proj (both branches) + fused softplus -> SP
    hipLaunchKernelGGL(dtproj_k, dim3(LSEQ / TS, D_INNER / TS, 2), dim3(256), 0, stream,
                       dt_proj_w, XDT0, dt_proj1_w, XDT1, SP0, SP1);

    // 7) chunk-parallel scan: 256-thread blocks, full co-residency
    hipLaunchKernelGGL(scan11_k, dim3(D_INNER / 2, 2), dim3(256), 0, stream,
                       SP0, CO0, XDT0, A_log, Dskip,
                       SP1, CO1, XDT1, A_log1, Dskip1,
                       GZ, RES0, RES1);

    // 8) merged: REST[l,d] = bf16(res0+res1) AND OWB = bf16(out_proj_w)
    hipLaunchKernelGGL(cvtT_add_owb_k, dim3(4096), dim3(256), 0, stream,
                       RES0, RES1, RESTB, out_proj_w, OWB);

    // 9) out_proj (bf16 MFMA, 128x64 tiles, split-K x4, 512 blocks) + reduce
    hipLaunchKernelGGL(mfma_out_k, dim3(16, 8, 4), dim3(256), 0, stream,
                       RESTB, OWB, P4);
    hipLaunchKernelGGL(reduce4_k, dim3((1 << 18) / 256), dim3(256), 0, stream,
                       P4, out);
}

// Round 17
// 202.730 us; speedup vs baseline: 1.0696x; 1.0696x over previous
//
#include <hip/hip_runtime.h>
#include <hip/hip_bf16.h>
#include <math.h>

// ---------------- problem constants ----------------
#define D_MODEL 1024
#define D_STATE 16
#define D_CONV  4
#define D_INNER 2048
#define DT_RANK 64
#define LSEQ    1024

typedef short bf16x8 __attribute__((ext_vector_type(8)));
typedef float f32x4  __attribute__((ext_vector_type(4)));

typedef const __attribute__((address_space(1))) unsigned int* gp1_t;
typedef __attribute__((address_space(3))) unsigned int* lp3_t;

__device__ __forceinline__ float softplus_f(float x) {
    const float sp = __logf(1.f + __expf(x));
    return (x > 20.f) ? x : sp;
}
__device__ __forceinline__ float silu_f(float x) {
    return x / (1.f + __expf(-x));
}
__device__ __forceinline__ unsigned short f2bf(float f) {
    union { float f; unsigned int u; } c; c.f = f;
    const unsigned int u = c.u;
    return (unsigned short)((u + 0x7FFFu + ((u >> 16) & 1u)) >> 16);
}

// ---------------- fused fp32->bf16 convert of all 4 GEMM inputs ----------------
__global__ __launch_bounds__(256)
void cvt_all_k(const float* __restrict__ w0, const float* __restrict__ xx,
               const float* __restrict__ w1, const float* __restrict__ xx1,
               unsigned short* __restrict__ WB, unsigned short* __restrict__ XB,
               unsigned short* __restrict__ WB1, unsigned short* __restrict__ X1B)
{
    const int i = blockIdx.x * 256 + threadIdx.x;
    const float* src; unsigned short* dst; int j;
    if (i < (1 << 20))            { src = w0;  dst = WB;  j = i; }
    else if (i < (5 << 18))       { src = xx;  dst = XB;  j = i - (1 << 20); }
    else if (i < (7 << 18))       { src = w1;  dst = WB1; j = i - (5 << 18); }
    else                          { src = xx1; dst = X1B; j = i - (7 << 18); }
    const float4 v = *(const float4*)&src[(size_t)j * 4];
    ushort4 o;
    o.x = f2bf(v.x); o.y = f2bf(v.y); o.z = f2bf(v.z); o.w = f2bf(v.w);
    *(ushort4*)&dst[(size_t)j * 4] = o;
}

// ---------------- transpose+add+convert REST[l][d] AND OWB convert (merged) ----------------
__global__ __launch_bounds__(256)
void cvtT_add_owb_k(const float* __restrict__ r0, const float* __restrict__ r1,
                    unsigned short* __restrict__ dst,
                    const float* __restrict__ ow, unsigned short* __restrict__ OWB)
{
    const int bx = blockIdx.x;
    if (bx >= 2048) {
        const int i = (bx - 2048) * 256 + threadIdx.x;
        const float4 v = *(const float4*)&ow[(size_t)i * 4];
        ushort4 o;
        o.x = f2bf(v.x); o.y = f2bf(v.y); o.z = f2bf(v.z); o.w = f2bf(v.w);
        *(ushort4*)&OWB[(size_t)i * 4] = o;
        return;
    }
    __shared__ float s[32][33];
    const int tx = threadIdx.x & 31, ty = threadIdx.x >> 5;
    const int lBase = (bx & 31) * 32, dBase = (bx >> 5) * 32;
    #pragma unroll
    for (int i = 0; i < 4; ++i) {
        const int d = dBase + ty + i * 8;
        const size_t off = (size_t)d * LSEQ + lBase + tx;
        s[ty + i * 8][tx] = r0[off] + r1[off];
    }
    __syncthreads();
    #pragma unroll
    for (int i = 0; i < 4; ++i) {
        const int l = lBase + ty + i * 8;
        dst[(size_t)l * D_INNER + dBase + tx] = f2bf(s[tx][ty + i * 8]);
    }
}

// ---------------- bf16 MFMA GEMM core (NT), 128x64 tile, 4 waves (2x2 of 64x32) ----------------
__device__ __forceinline__
void mfma_tile64(const unsigned short* __restrict__ A, const unsigned short* __restrict__ B,
                 float* __restrict__ C, int N, int K, int lda, int mBase, int nBase, int siluRow)
{
    __shared__ unsigned short AsL[128 * 32];
    __shared__ unsigned short BsL[64 * 32];
    const int tid = threadIdx.x;
    const int lane = tid & 63, w = tid >> 6;
    const int wr = w >> 1, wc = w & 1;
    const int l15 = lane & 15, l4 = lane >> 4;

    f32x4 acc[4][2] = {};
    const int stRow = tid >> 2;
    const int stCol = (tid & 3) * 8;
    const int ldsOff = w * 512;

    for (int kb = 0; kb < K; kb += 32) {
        #pragma unroll
        for (int it = 0; it < 2; ++it) {
            const int r = it * 64 + stRow;
            __builtin_amdgcn_global_load_lds(
                (gp1_t)&A[(size_t)(mBase + r) * lda + kb + stCol],
                (lp3_t)&AsL[it * 2048 + ldsOff], 16, 0, 0);
        }
        __builtin_amdgcn_global_load_lds(
            (gp1_t)&B[(size_t)(nBase + stRow) * lda + kb + stCol],
            (lp3_t)&BsL[ldsOff], 16, 0, 0);
        __syncthreads();
        bf16x8 af[4], bfr[2];
        #pragma unroll
        for (int i = 0; i < 4; ++i)
            af[i] = *(const bf16x8*)&AsL[(wr * 64 + i * 16 + l15) * 32 + l4 * 8];
        #pragma unroll
        for (int j = 0; j < 2; ++j)
            bfr[j] = *(const bf16x8*)&BsL[(wc * 32 + j * 16 + l15) * 32 + l4 * 8];
        #pragma unroll
        for (int i = 0; i < 4; ++i)
            #pragma unroll
            for (int j = 0; j < 2; ++j)
                acc[i][j] = __builtin_amdgcn_mfma_f32_16x16x32_bf16(af[i], bfr[j], acc[i][j], 0, 0, 0);
        __syncthreads();
    }

    #pragma unroll
    for (int i = 0; i < 4; ++i) {
        const int row0 = mBase + wr * 64 + i * 16 + l4 * 4;
        #pragma unroll
        for (int j = 0; j < 2; ++j) {
            const int col = nBase + wc * 32 + j * 16 + l15;
            #pragma unroll
            for (int r = 0; r < 4; ++r) {
                float v = acc[i][j][r];
                if (row0 + r >= siluRow) v = silu_f(v);
                C[(size_t)(row0 + r) * N + col] = v;
            }
        }
    }
}

__global__ __launch_bounds__(256)
void mfma_in_k(const unsigned short* __restrict__ WB, const unsigned short* __restrict__ XB,
               const unsigned short* __restrict__ WB1, const unsigned short* __restrict__ X1B,
               float* __restrict__ XZ, float* __restrict__ X1P)
{
    const int by = blockIdx.y;
    if (by < 32)
        mfma_tile64(WB, XB, XZ, 1024, 1024, 1024, by * 128, blockIdx.x * 64, 2048);
    else
        mfma_tile64(WB1, X1B, X1P, 1024, 1024, 1024, (by - 32) * 128, blockIdx.x * 64, 1 << 30);
}

__global__ __launch_bounds__(256)
void mfma_out_k(const unsigned short* __restrict__ RESTB, const unsigned short* __restrict__ OWB,
                float* __restrict__ P4)
{
    const int z = blockIdx.z;
    mfma_tile64(RESTB + z * 512, OWB + z * 512, P4 + (size_t)z * (1 << 20),
                1024, 512, 2048, blockIdx.y * 128, blockIdx.x * 64, 1 << 30);
}

__global__ __launch_bounds__(256)
void reduce4_k(const float* __restrict__ P, float* __restrict__ out)
{
    const int i = blockIdx.x * 256 + threadIdx.x;
    const size_t o = (size_t)i * 4;
    float4 s = *(const float4*)&P[o];
    #pragma unroll
    for (int z = 1; z < 4; ++z) {
        const float4 v = *(const float4*)&P[(size_t)z * (1 << 20) + o];
        s.x += v.x; s.y += v.y; s.z += v.z; s.w += v.w;
    }
    *(float4*)&out[o] = s;
}

// ---------------- x_proj split-K, single launch ----------------
constexpr int TS = 64;
constexpr int KT = 16;
constexpr int LP = 4;

__global__ __launch_bounds__(256)
void xproj_k(const float* __restrict__ xw0, const float* __restrict__ co0,
             const float* __restrict__ xw1, const float* __restrict__ co1,
             float* __restrict__ P0, float* __restrict__ P1)
{
    const int br = blockIdx.z >> 3;
    const int sl = blockIdx.z & 7;
    const float* A = (br ? xw1 : xw0) + sl * 256;
    const float* B = (br ? co1 : co0) + (size_t)sl * 256 * LSEQ;
    float* C = (br ? P1 : P0) + (size_t)sl * 96 * LSEQ;

    __shared__ float As[KT][TS + LP];
    __shared__ float BsL[16 * 64];
    const int tid = threadIdx.x;
    const int tx = tid & 15, ty = tid >> 4;
    const int mBase = blockIdx.y * TS;
    const int nBase = blockIdx.x * TS;

    float acc[4][4] = {};
    const int ar = tid >> 2;
    const int ak = (tid & 3) * 4;
    const int ldsOffB = (tid >> 6) * 256;

    for (int kb = 0; kb < 256; kb += KT) {
        {
            const int gm = mBase + ar;
            float4 av = make_float4(0.f, 0.f, 0.f, 0.f);
            if (gm < 96) av = *(const float4*)&A[(size_t)gm * D_INNER + kb + ak];
            As[ak + 0][ar] = av.x;
            As[ak + 1][ar] = av.y;
            As[ak + 2][ar] = av.z;
            As[ak + 3][ar] = av.w;
        }
        __builtin_amdgcn_global_load_lds(
            (gp1_t)&B[(size_t)(kb + (tid >> 4)) * LSEQ + nBase + (tid & 15) * 4],
            (lp3_t)&BsL[ldsOffB], 16, 0, 0);
        __syncthreads();
        #pragma unroll
        for (int k = 0; k < KT; ++k) {
            float4 a = *(const float4*)&As[k][ty * 4];
            float4 b = *(const float4*)&BsL[k * 64 + tx * 4];
            float av[4] = {a.x, a.y, a.z, a.w};
            float bv[4] = {b.x, b.y, b.z, b.w};
            #pragma unroll
            for (int i = 0; i < 4; ++i)
                #pragma unroll
                for (int j = 0; j < 4; ++j)
                    acc[i][j] = fmaf(av[i], bv[j], acc[i][j]);
        }
        __syncthreads();
    }

    #pragma unroll
    for (int i = 0; i < 4; ++i) {
        const int m = mBase + ty * 4 + i;
        if (m >= 96) continue;
        #pragma unroll
        for (int j = 0; j < 4; ++j)
            C[(size_t)m * LSEQ + nBase + tx * 4 + j] = acc[i][j];
    }
}

// ---------------- reduce split-K partials + transpose + interleave B/C ----------------
__global__ __launch_bounds__(256)
void reduceT_k(const float* __restrict__ P0, const float* __restrict__ P1,
               float* __restrict__ xdT0, float* __restrict__ xdT1)
{
    const int idx = blockIdx.x * 256 + threadIdx.x;
    const int k = idx & 127;
    const int l = (idx >> 7) & (LSEQ - 1);
    const int br = idx >> 17;
    if (k >= 96) return;
    const int srck = (k < 64) ? k : (64 + ((k - 64) >> 1) + ((k & 1) << 4));
    const float* P = br ? P1 : P0;
    float s = 0.f;
    #pragma unroll
    for (int sl = 0; sl < 8; ++sl)
        s += P[(size_t)sl * 96 * LSEQ + (size_t)srck * LSEQ + l];
    float* o = br ? xdT1 : xdT0;
    o[(size_t)l * 96 + k] = s;
}

// ---------------- dt_proj (both branches) + fused softplus ----------------
__global__ __launch_bounds__(256)
void dtproj_k(const float* __restrict__ dtw0, const float* __restrict__ xdT0,
              const float* __restrict__ dtw1, const float* __restrict__ xdT1,
              float* __restrict__ SP0, float* __restrict__ SP1)
{
    const int br = blockIdx.z;
    const float* A = br ? dtw1 : dtw0;
    const float* B = br ? xdT1 : xdT0;
    float* C = br ? SP1 : SP0;

    __shared__ float As[KT][TS + LP];
    __shared__ float Bs[KT][TS + LP];
    const int tid = threadIdx.x;
    const int tx = tid & 15, ty = tid >> 4;
    const int mBase = blockIdx.y * TS;
    const int nBase = blockIdx.x * TS;

    float acc[4][4] = {};
    const int ar = tid >> 2;
    const int ak = (tid & 3) * 4;

    for (int kb = 0; kb < DT_RANK; kb += KT) {
        {
            const float4 av = *(const float4*)&A[(size_t)(mBase + ar) * DT_RANK + kb + ak];
            As[ak + 0][ar] = av.x;
            As[ak + 1][ar] = av.y;
            As[ak + 2][ar] = av.z;
            As[ak + 3][ar] = av.w;
        }
        {
            const float4 bv = *(const float4*)&B[(size_t)(nBase + ar) * 96 + kb + ak];
            Bs[ak + 0][ar] = bv.x;
            Bs[ak + 1][ar] = bv.y;
            Bs[ak + 2][ar] = bv.z;
            Bs[ak + 3][ar] = bv.w;
        }
        __syncthreads();
        #pragma unroll
        for (int k = 0; k < KT; ++k) {
            float4 a = *(const float4*)&As[k][ty * 4];
            float4 b = *(const float4*)&Bs[k][tx * 4];
            float av[4] = {a.x, a.y, a.z, a.w};
            float bv[4] = {b.x, b.y, b.z, b.w};
            #pragma unroll
            for (int i = 0; i < 4; ++i)
                #pragma unroll
                for (int j = 0; j < 4; ++j)
                    acc[i][j] = fmaf(av[i], bv[j], acc[i][j]);
        }
        __syncthreads();
    }

    #pragma unroll
    for (int i = 0; i < 4; ++i)
        #pragma unroll
        for (int j = 0; j < 4; ++j)
            C[(size_t)(mBase + ty * 4 + i) * LSEQ + nBase + tx * 4 + j] = softplus_f(acc[i][j]);
}

// ---------------- depthwise causal conv1d + SiLU ----------------
__global__ __launch_bounds__(256)
void conv_silu_k(const float* __restrict__ xa, const float* __restrict__ x1p,
                 const float* __restrict__ w0, const float* __restrict__ b0,
                 const float* __restrict__ w1, const float* __restrict__ b1,
                 float* __restrict__ co0, float* __restrict__ co1)
{
    const int idx = blockIdx.x * blockDim.x + threadIdx.x;
    const int br  = idx >> 21;
    const int rem = idx & ((1 << 21) - 1);
    const int d = rem >> 10;
    const int l = rem & (LSEQ - 1);

    const float* xin = br ? x1p : xa;
    const float* w   = br ? w1 : w0;
    const float* bb  = br ? b1 : b0;
    float* out       = br ? co1 : co0;

    const float* row = xin + (size_t)d * LSEQ;
    float acc = bb[d];
    #pragma unroll
    for (int j = 0; j < D_CONV; ++j) {
        const int li = l - (D_CONV - 1) + j;
        const float xv = (li >= 0) ? row[li] : 0.f;
        acc = fmaf(w[d * D_CONV + j], xv, acc);
    }
    out[rem] = silu_f(acc);
}

// ---------------- chunk-parallel scan: 2 ch/block + coalesced LDS-buffered stores ----------------
// (round-15 proven best: 85.5 us) grid (D_INNER/2, 2), 512 thr = 32 chunks x 16 states.
__global__ __launch_bounds__(512)
void scan10_k(const float* __restrict__ sp0, const float* __restrict__ u0,
              const float* __restrict__ xdT0,
              const float* __restrict__ Al0, const float* __restrict__ Dk0,
              const float* __restrict__ sp1, const float* __restrict__ u1,
              const float* __restrict__ xdT1,
              const float* __restrict__ Al1, const float* __restrict__ Dk1,
              const float* __restrict__ gz,
              float* __restrict__ res0, float* __restrict__ res1)
{
    const int d0  = blockIdx.x * 2;
    const int br  = blockIdx.y;
    const int tid = threadIdx.x;
    const int n   = tid & 15;
    const int c   = tid >> 4;          // 0..31

    const float* __restrict__ sp  = br ? sp1  : sp0;
    const float* __restrict__ u   = br ? u1   : u0;
    const float* __restrict__ xdT = br ? xdT1 : xdT0;
    const float* __restrict__ Al  = br ? Al1  : Al0;
    const float* __restrict__ Dk  = br ? Dk1  : Dk0;
    float* __restrict__ res       = br ? res1 : res0;

    float Adn[2], Dd[2];
    const float* srow[2]; const float* urow[2]; const float* grow[2]; float* orow[2];
    #pragma unroll
    for (int g = 0; g < 2; ++g) {
        Adn[g] = -__expf(Al[(d0 + g) * D_STATE + n]);
        Dd[g]  = Dk[d0 + g];
        srow[g] = sp + (size_t)(d0 + g) * LSEQ;
        urow[g] = u  + (size_t)(d0 + g) * LSEQ;
        grow[g] = gz + (size_t)(d0 + g) * LSEQ;
        orow[g] = res + (size_t)(d0 + g) * LSEQ;
    }
    const float* __restrict__ bc = xdT + 64 + 2 * n;
    const int t0 = c * 32;

    // ---- phase 1: chunk-local (a, b) per channel
    float a[2] = {1.f, 1.f};
    float b[2] = {0.f, 0.f};
    for (int tt = 0; tt < 32; tt += 4) {
        float2 bcv[4];
        #pragma unroll
        for (int j = 0; j < 4; ++j)
            bcv[j] = *(const float2*)&bc[(size_t)(t0 + tt + j) * 96];
        #pragma unroll
        for (int g = 0; g < 2; ++g) {
            const float4 s4 = *(const float4*)&srow[g][t0 + tt];
            const float4 u4 = *(const float4*)&urow[g][t0 + tt];
            const float sps[4] = {s4.x, s4.y, s4.z, s4.w};
            const float uvs[4] = {u4.x, u4.y, u4.z, u4.w};
            #pragma unroll
            for (int j = 0; j < 4; ++j) {
                const float dA = __expf(sps[j] * Adn[g]);
                a[g] *= dA;
                b[g] = fmaf(dA, b[g], sps[j] * uvs[j] * bcv[j].x);
            }
        }
    }

    __shared__ float sAm[32][16][2];
    __shared__ float sBm[32][16][2];
    __shared__ float sHm[32][16][2];
    __shared__ float yBuf[2][1024];
    #pragma unroll
    for (int g = 0; g < 2; ++g) { sAm[c][n][g] = a[g]; sBm[c][n][g] = b[g]; }
    __syncthreads();

    // ---- phase 2: serial exclusive scan over 32 chunks (32 threads: one per (n, g))
    if (tid < 32) {
        const int n2 = tid & 15, g2 = tid >> 4;
        float hb = 0.f;
        #pragma unroll
        for (int cc = 0; cc < 32; ++cc) {
            sHm[cc][n2][g2] = hb;
            hb = fmaf(sAm[cc][n2][g2], hb, sBm[cc][n2][g2]);
        }
    }
    __syncthreads();

    // ---- phase 3: re-run chunk from h_start; y -> LDS buffer
    float h[2];
    #pragma unroll
    for (int g = 0; g < 2; ++g) h[g] = sHm[c][n][g];

    for (int tt = 0; tt < 32; tt += 4) {
        float2 bcv[4];
        #pragma unroll
        for (int j = 0; j < 4; ++j)
            bcv[j] = *(const float2*)&bc[(size_t)(t0 + tt + j) * 96];
        #pragma unroll
        for (int g = 0; g < 2; ++g) {
            const float4 s4 = *(const float4*)&srow[g][t0 + tt];
            const float4 u4 = *(const float4*)&urow[g][t0 + tt];
            const float4 g4 = *(const float4*)&grow[g][t0 + tt];
            const float sps[4] = {s4.x, s4.y, s4.z, s4.w};
            const float uvs[4] = {u4.x, u4.y, u4.z, u4.w};
            const float gzs[4] = {g4.x, g4.y, g4.z, g4.w};
            float y4[4];
            #pragma unroll
            for (int j = 0; j < 4; ++j) {
                const float dA = __expf(sps[j] * Adn[g]);
                h[g] = fmaf(dA, h[g], sps[j] * uvs[j] * bcv[j].x);
                float y = h[g] * bcv[j].y;
                y += __shfl_xor(y, 1);
                y += __shfl_xor(y, 2);
                y += __shfl_xor(y, 4);
                y += __shfl_xor(y, 8);
                y4[j] = y;
            }
            if (n == 0) {
                float4 o;
                float* op = (float*)&o;
                #pragma unroll
                for (int j = 0; j < 4; ++j)
                    op[j] = (y4[j] + Dd[g] * uvs[j]) * gzs[j];
                *(float4*)&yBuf[g][t0 + tt] = o;
            }
        }
    }
    __syncthreads();

    // ---- coalesced store: 512 threads x float4 = 2 channels x 4 KB contiguous
    {
        const int g2 = tid >> 8;          // 0..1
        const int i4 = (tid & 255) << 2;  // 0..1020
        *(float4*)&orow[g2][i4] = *(const float4*)&yBuf[g2][i4];
    }
}

// ---------------- launcher ----------------
extern "C" void kernel_launch(void* const* d_in, const int* in_sizes, int n_in,
                              void* d_out, int out_size, void* d_ws, size_t ws_size,
                              hipStream_t stream)
{
    const float* x          = (const float*)d_in[0];
    const float* x1         = (const float*)d_in[1];
    const float* in_proj_w  = (const float*)d_in[2];
    const float* in_proj1_w = (const float*)d_in[3];
    const float* conv_w     = (const float*)d_in[4];
    const float* conv_b     = (const float*)d_in[5];
    const float* conv1_w    = (const float*)d_in[6];
    const float* conv1_b    = (const float*)d_in[7];
    const float* x_proj_w   = (const float*)d_in[8];
    const float* x_proj1_w  = (const float*)d_in[9];
    const float* dt_proj_w  = (const float*)d_in[10];
    const float* dt_proj1_w = (const float*)d_in[11];
    const float* A_log      = (const float*)d_in[12];
    const float* A_log1     = (const float*)d_in[13];
    const float* Dskip      = (const float*)d_in[14];
    const float* Dskip1     = (const float*)d_in[15];
    const float* out_proj_w = (const float*)d_in[16];

    float* ws = (float*)d_ws;
    const size_t CH = (size_t)D_INNER * LSEQ;
    const size_t XD = (size_t)96 * LSEQ;
    const size_t F  = 5 * CH + 2 * XD;

    float* XA    = ws;
    float* RES0  = ws;                   // over dead xa
    float* GZ    = ws + CH;
    float* X1P   = ws + 2 * CH;
    float* RES1  = ws + 2 * CH;          // over dead x1p
    float* CO0   = ws + 3 * CH;
    float* CO1   = ws + 4 * CH;
    float* P4    = ws + 3 * CH;          // out_proj split-K partials over dead co0/co1
    float* XDT0  = ws + 5 * CH;
    float* XDT1  = XDT0 + XD;
    float* XZ    = ws;

    unsigned short* WB  = (unsigned short*)(ws + F);
    unsigned short* XB  = (unsigned short*)(ws + F + 2097152);
    unsigned short* WB1 = (unsigned short*)(ws + F + 2097152 + 524288);
    unsigned short* X1B = (unsigned short*)(ws + F + 2097152 + 524288 + 1048576);
    float* P0  = ws + F;
    float* P1  = P0 + 8 * XD;
    float* SP0 = ws + F;
    float* SP1 = ws + F + CH;
    unsigned short* OWB   = (unsigned short*)(ws + F);
    unsigned short* RESTB = (unsigned short*)(ws + F + CH / 2);

    float* out = (float*)d_out;

    // 1) convert all four GEMM inputs to bf16
    hipLaunchKernelGGL(cvt_all_k, dim3((2 << 20) / 256), dim3(256), 0, stream,
                       in_proj_w, x, in_proj1_w, x1, WB, XB, WB1, X1B);

    // 2) in_proj + in_proj1 (merged bf16 MFMA, 128x64 tiles, 768 blocks = 3/CU)
    hipLaunchKernelGGL(mfma_in_k, dim3(16, 48), dim3(256), 0, stream,
                       WB, XB, WB1, X1B, XZ, X1P);

    // 3) causal conv + silu
    hipLaunchKernelGGL(conv_silu_k, dim3(2 * D_INNER * LSEQ / 256), dim3(256), 0, stream,
                       XA, X1P, conv_w, conv_b, conv1_w, conv1_b, CO0, CO1);

    // 4) x_proj split-K (one launch, 512 blocks)
    hipLaunchKernelGGL(xproj_k, dim3(LSEQ / TS, 2, 16), dim3(256), 0, stream,
                       x_proj_w, CO0, x_proj1_w, CO1, P0, P1);

    // 5) reduce partials -> xdT [L][96] interleaved
    hipLaunchKernelGGL(reduceT_k, dim3(2 * LSEQ * 128 / 256), dim3(256), 0, stream,
                       P0, P1, XDT0, XDT1);

    // 6) dt_proj (both branches) + fused softplus -> SP
    hipLaunchKernelGGL(dtproj_k, dim3(LSEQ / TS, D_INNER / TS, 2), dim3(256), 0, stream,
                       dt_proj_w, XDT0, dt_proj1_w, XDT1, SP0, SP1);

    // 7) chunk-parallel scan: 2 channels/block, coalesced stores
    hipLaunchKernelGGL(scan10_k, dim3(D_INNER / 2, 2), dim3(512), 0, stream,
                       SP0, CO0, XDT0, A_log, Dskip,
                       SP1, CO1, XDT1, A_log1, Dskip1,
                       GZ, RES0, RES1);

    // 8) merged: REST[l,d] = bf16(res0+res1) AND OWB = bf16(out_proj_w)
    hipLaunchKernelGGL(cvtT_add_owb_k, dim3(4096), dim3(256), 0, stream,
                       RES0, RES1, RESTB, out_proj_w, OWB);

    // 9) out_proj (bf16 MFMA, 128x64 tiles, split-K x4, 512 blocks) + reduce
    hipLaunchKernelGGL(mfma_out_k, dim3(16, 8, 4), dim3(256), 0, stream,
                       RESTB, OWB, P4);
    hipLaunchKernelGGL(reduce4_k, dim3((1 << 18) / 256), dim3(256), 0, stream,
                       P4, out);
}